// Round 1
// baseline (154.988 us; speedup 1.0000x reference)
//
#include <hip/hip_runtime.h>
#include <hip/hip_bf16.h>

typedef __bf16 bf16x8 __attribute__((ext_vector_type(8)));
typedef float  f32x4  __attribute__((ext_vector_type(4)));
typedef unsigned short u16;
typedef unsigned int   u32;

__device__ __forceinline__ u16 f2b(float x) {
  __bf16 b = (__bf16)x;
  return __builtin_bit_cast(u16, b);
}

__device__ __forceinline__ void gload_lds16(const u16* g, u16* l) {
  __builtin_amdgcn_global_load_lds(
      (const __attribute__((address_space(1))) void*)g,
      (__attribute__((address_space(3))) void*)l, 16, 0, 0);
}

// ---------------- convert q,k,v f32 -> bf16 (fused in one launch) -------------
#define Q4 1048576   // 2*2048*1024/4
#define K4 262144    // 2*512*1024/4
__global__ __launch_bounds__(256) void cvt3_kernel(
    const float* __restrict__ q, const float* __restrict__ k, const float* __restrict__ v,
    u16* __restrict__ qb, u16* __restrict__ kb, u16* __restrict__ vb)
{
  int i = blockIdx.x * 256 + threadIdx.x;
  const float* src; u16* dst; int off;
  if (i < Q4)            { src = q; dst = qb; off = i; }
  else if (i < Q4 + K4)  { src = k; dst = kb; off = i - Q4; }
  else                   { src = v; dst = vb; off = i - Q4 - K4; }
  float4 x = ((const float4*)src)[off];
  ushort4 r;
  r.x = f2b(x.x); r.y = f2b(x.y); r.z = f2b(x.z); r.w = f2b(x.w);
  ((ushort4*)dst)[off] = r;
}

// ---------------- transpose + convert weights: W[1024][1024] f32 -> Wt[n][k] bf16
__global__ __launch_bounds__(256) void transpose_cvt_kernel(
    const float* __restrict__ W0, const float* __restrict__ W1,
    const float* __restrict__ W2, const float* __restrict__ W3,
    u16* __restrict__ T0, u16* __restrict__ T1, u16* __restrict__ T2, u16* __restrict__ T3)
{
  __shared__ float tile[32][33];
  int z = blockIdx.z;
  const float* W = (z == 0) ? W0 : (z == 1) ? W1 : (z == 2) ? W2 : W3;
  u16* T = (z == 0) ? T0 : (z == 1) ? T1 : (z == 2) ? T2 : T3;
  int tx = threadIdx.x & 31, ty = threadIdx.x >> 5;
  int c0 = blockIdx.x * 32, r0 = blockIdx.y * 32;
#pragma unroll
  for (int i = 0; i < 4; ++i)
    tile[ty + i * 8][tx] = W[(size_t)(r0 + ty + i * 8) * 1024 + c0 + tx];
  __syncthreads();
#pragma unroll
  for (int i = 0; i < 4; ++i)
    T[(size_t)(c0 + ty + i * 8) * 1024 + r0 + tx] = f2b(tile[tx][ty + i * 8]);
}

// ---------------- bf16 MFMA GEMM: C[M,N] = A[M,K] * Bt[N,K]^T ----------------
// BM=BN=128, BK=64, 256 threads (4 waves, 2x2), each wave 64x64 (4x4 frags 16x16)
// LDS rows are 128B, XOR-swizzled by ((row&7)<<4) for conflict-free ds_read_b128.
template <int OUTF32>
__global__ __launch_bounds__(256, 2) void gemm_bt_kernel(
    const u16* __restrict__ A, const u16* __restrict__ Bt, void* __restrict__ C,
    int M, int N, int K)
{
  __shared__ u16 As[128 * 64];
  __shared__ u16 Bs[128 * 64];
  const int tid = threadIdx.x;
  const int wave = tid >> 6, lane = tid & 63;
  const int nbx = N >> 7;
  const int bx = blockIdx.x % nbx, by = blockIdx.x / nbx;
  const int row0 = by << 7, col0 = bx << 7;
  const int wm = wave >> 1, wn = wave & 1;

  f32x4 acc[4][4] = {};

  // staging: per wave-call 8 rows x 128B; lane -> row (lane>>3), slot (lane&7)
  const int srow = lane >> 3;
  const int sslot = lane & 7;
  const int scol = ((sslot ^ srow) << 3);  // element col within 64-elem row (swizzle inverse)

  for (int k0 = 0; k0 < K; k0 += 64) {
#pragma unroll
    for (int i = 0; i < 4; ++i) {
      int rbase = (wave << 5) + (i << 3);
      const u16* ga = A + (size_t)(row0 + rbase + srow) * K + k0 + scol;
      gload_lds16(ga, &As[rbase << 6]);
      const u16* gb = Bt + (size_t)(col0 + rbase + srow) * K + k0 + scol;
      gload_lds16(gb, &Bs[rbase << 6]);
    }
    __syncthreads();
#pragma unroll
    for (int kk = 0; kk < 2; ++kk) {
      bf16x8 af[4], bfr[4];
      int colb = (kk << 6) + ((lane >> 4) << 4);  // byte col within row
#pragma unroll
      for (int m = 0; m < 4; ++m) {
        int r = (wm << 6) + (m << 4) + (lane & 15);
        af[m] = *(const bf16x8*)((const char*)As + (r << 7) + (colb ^ ((r & 7) << 4)));
      }
#pragma unroll
      for (int n = 0; n < 4; ++n) {
        int r = (wn << 6) + (n << 4) + (lane & 15);
        bfr[n] = *(const bf16x8*)((const char*)Bs + (r << 7) + (colb ^ ((r & 7) << 4)));
      }
#pragma unroll
      for (int m = 0; m < 4; ++m)
#pragma unroll
        for (int n = 0; n < 4; ++n)
          acc[m][n] = __builtin_amdgcn_mfma_f32_16x16x32_bf16(af[m], bfr[n], acc[m][n], 0, 0, 0);
    }
    __syncthreads();
  }

  const int crow = (lane >> 4) << 2;
  const int ccol = lane & 15;
#pragma unroll
  for (int m = 0; m < 4; ++m) {
#pragma unroll
    for (int n = 0; n < 4; ++n) {
      int r = row0 + (wm << 6) + (m << 4) + crow;
      int c = col0 + (wn << 6) + (n << 4) + ccol;
#pragma unroll
      for (int reg = 0; reg < 4; ++reg) {
        if (OUTF32) ((float*)C)[(size_t)(r + reg) * N + c] = acc[m][n][reg];
        else        ((u16*)C)[(size_t)(r + reg) * N + c] = f2b(acc[m][n][reg]);
      }
    }
  }
}

// ---------------- strided-local attention ------------------------------------
// Q[b,j,h,:] attends keys kc0(j)..kc0(j)+31, kc0(j)=floor((j-124)/4); valid iff kc0+t>=0.
// Block = (jtile of 64 queries, h, b), 256 threads (4 waves, 16 queries each).
#define KW 48
#define LPAD 68
__global__ __launch_bounds__(256) void attn_kernel(
    const u16* __restrict__ Qp, const u16* __restrict__ Kp,
    const u16* __restrict__ Vp, u16* __restrict__ Ob)
{
  __shared__ float Kl[KW][LPAD];
  __shared__ float Vl[KW][LPAD];
  __shared__ float Ql[64][LPAD];

  const int jt = blockIdx.x, h = blockIdx.y, b = blockIdx.z;
  const int j0 = jt * 64;
  const int kbase = (j0 - 124) >> 2;  // floor((j0-124)/4)
  const int tid = threadIdx.x;

  for (int idx = tid; idx < KW * 64; idx += 256) {
    int row = idx >> 6, d = idx & 63;
    int key = kbase + row;
    key = key < 0 ? 0 : (key > 511 ? 511 : key);
    size_t off = ((size_t)(b * 512 + key) * 1024) + h * 64 + d;
    Kl[row][d] = (float)((const __bf16*)Kp)[off];
    Vl[row][d] = (float)((const __bf16*)Vp)[off];
  }
  for (int idx = tid; idx < 64 * 64; idx += 256) {
    int row = idx >> 6, d = idx & 63;
    size_t off = ((size_t)(b * 2048 + j0 + row) * 1024) + h * 64 + d;
    Ql[row][d] = (float)((const __bf16*)Qp)[off];
  }
  __syncthreads();

  const int wave = tid >> 6, lane = tid & 63;
  const int t = lane & 31, half = lane >> 5;

  for (int i = 0; i < 16; ++i) {
    int jq = wave * 16 + i;
    int rof = jq >> 2;
    int kc0 = kbase + rof;
    int krow = rof + t;

    float s = 0.f;
#pragma unroll
    for (int dq = 0; dq < 32; dq += 4) {
      float4 kv = *(const float4*)&Kl[krow][half * 32 + dq];
      float4 qv = *(const float4*)&Ql[jq][half * 32 + dq];
      s += kv.x * qv.x + kv.y * qv.y + kv.z * qv.z + kv.w * qv.w;
    }
    s += __shfl_xor(s, 32);
    s *= 0.125f;
    bool valid = (kc0 + t) >= 0;
    s = valid ? s : -__builtin_inff();

    float m = s;
#pragma unroll
    for (int dl = 16; dl >= 1; dl >>= 1) m = fmaxf(m, __shfl_xor(m, dl));
    float e = valid ? __expf(s - m) : 0.f;
    float sum = e;
#pragma unroll
    for (int dl = 16; dl >= 1; dl >>= 1) sum += __shfl_xor(sum, dl);
    float p = e / sum;

    float o = 0.f;
#pragma unroll
    for (int tt = 0; tt < 32; ++tt) {
      float pv = __shfl(p, tt);
      o += pv * Vl[rof + tt][lane];
    }
    size_t off = ((size_t)(b * 2048 + j0 + jq) * 1024) + h * 64 + lane;
    Ob[off] = f2b(o);
  }
}

extern "C" void kernel_launch(void* const* d_in, const int* in_sizes, int n_in,
                              void* d_out, int out_size, void* d_ws, size_t ws_size,
                              hipStream_t stream) {
  const float* q  = (const float*)d_in[0];
  const float* k  = (const float*)d_in[1];
  const float* v  = (const float*)d_in[2];
  const float* Wq = (const float*)d_in[3];
  const float* Wk = (const float*)d_in[4];
  const float* Wv = (const float*)d_in[5];
  const float* Wo = (const float*)d_in[6];

  char* ws = (char*)d_ws;
  const size_t MB = 1u << 20;
  u16* qb  = (u16*)(ws + 0 * MB);    // 8 MB
  u16* kb  = (u16*)(ws + 8 * MB);    // 2 MB
  u16* vb  = (u16*)(ws + 10 * MB);   // 2 MB
  u16* Wqt = (u16*)(ws + 12 * MB);   // 2 MB
  u16* Wkt = (u16*)(ws + 14 * MB);
  u16* Wvt = (u16*)(ws + 16 * MB);
  u16* Wot = (u16*)(ws + 18 * MB);
  u16* Qp  = (u16*)(ws + 20 * MB);   // 8 MB
  u16* Kp  = (u16*)(ws + 28 * MB);   // 2 MB
  u16* Vp  = (u16*)(ws + 30 * MB);   // 2 MB
  u16* Ob  = (u16*)(ws + 32 * MB);   // 8 MB  (total 40 MB)

  // 1) convert inputs to bf16
  cvt3_kernel<<<6144, 256, 0, stream>>>(q, k, v, qb, kb, vb);
  // 2) transpose+convert all 4 weight matrices
  transpose_cvt_kernel<<<dim3(32, 32, 4), 256, 0, stream>>>(Wq, Wk, Wv, Wo, Wqt, Wkt, Wvt, Wot);
  // 3) projections
  gemm_bt_kernel<0><<<256, 256, 0, stream>>>(qb, Wqt, Qp, 4096, 1024, 1024);
  gemm_bt_kernel<0><<<64, 256, 0, stream>>>(kb, Wkt, Kp, 1024, 1024, 1024);
  gemm_bt_kernel<0><<<64, 256, 0, stream>>>(vb, Wvt, Vp, 1024, 1024, 1024);
  // 4) attention
  attn_kernel<<<dim3(32, 16, 2), 256, 0, stream>>>(Qp, Kp, Vp, Ob);
  // 5) output projection (f32 out)
  gemm_bt_kernel<1><<<256, 256, 0, stream>>>(Ob, Wot, d_out, 4096, 1024, 1024);
}

// Round 2
// 86.941 us; speedup vs baseline: 1.7827x; 1.7827x over previous
//
#include <hip/hip_runtime.h>
#include <hip/hip_bf16.h>

typedef __bf16 bf16x8 __attribute__((ext_vector_type(8)));
typedef float  f32x4  __attribute__((ext_vector_type(4)));
typedef unsigned short u16;
typedef unsigned int   u32;

__device__ __forceinline__ u16 f2b(float x) {
  __bf16 b = (__bf16)x;
  return __builtin_bit_cast(u16, b);
}

__device__ __forceinline__ void gload_lds16(const u16* g, u16* l) {
  __builtin_amdgcn_global_load_lds(
      (const __attribute__((address_space(1))) void*)g,
      (__attribute__((address_space(3))) void*)l, 16, 0, 0);
}

// ---------------- convert q,k,v f32 -> bf16 (fused in one launch) -------------
#define Q4 1048576   // 2*2048*1024/4
#define K4 262144    // 2*512*1024/4
__global__ __launch_bounds__(256) void cvt3_kernel(
    const float* __restrict__ q, const float* __restrict__ k, const float* __restrict__ v,
    u16* __restrict__ qb, u16* __restrict__ kb, u16* __restrict__ vb)
{
  int i = blockIdx.x * 256 + threadIdx.x;
  const float* src; u16* dst; int off;
  if (i < Q4)            { src = q; dst = qb; off = i; }
  else if (i < Q4 + K4)  { src = k; dst = kb; off = i - Q4; }
  else                   { src = v; dst = vb; off = i - Q4 - K4; }
  float4 x = ((const float4*)src)[off];
  ushort4 r;
  r.x = f2b(x.x); r.y = f2b(x.y); r.z = f2b(x.z); r.w = f2b(x.w);
  ((ushort4*)dst)[off] = r;
}

// ---------------- transpose + convert weights: W[1024][1024] f32 -> Wt[n][k] bf16
__global__ __launch_bounds__(256) void transpose_cvt_kernel(
    const float* __restrict__ W0, const float* __restrict__ W1,
    const float* __restrict__ W2, const float* __restrict__ W3,
    u16* __restrict__ T0, u16* __restrict__ T1, u16* __restrict__ T2, u16* __restrict__ T3)
{
  __shared__ float tile[32][33];
  int z = blockIdx.z;
  const float* W = (z == 0) ? W0 : (z == 1) ? W1 : (z == 2) ? W2 : W3;
  u16* T = (z == 0) ? T0 : (z == 1) ? T1 : (z == 2) ? T2 : T3;
  int tx = threadIdx.x & 31, ty = threadIdx.x >> 5;
  int c0 = blockIdx.x * 32, r0 = blockIdx.y * 32;
#pragma unroll
  for (int i = 0; i < 4; ++i)
    tile[ty + i * 8][tx] = W[(size_t)(r0 + ty + i * 8) * 1024 + c0 + tx];
  __syncthreads();
#pragma unroll
  for (int i = 0; i < 4; ++i)
    T[(size_t)(c0 + ty + i * 8) * 1024 + r0 + tx] = f2b(tile[tx][ty + i * 8]);
}

// ---------------- bf16 MFMA GEMM: C[M,N] = A[M,K] * Bt[N,K]^T ----------------
// BM=BN=128, BK=64, 256 threads (4 waves, 2x2), each wave 64x64 (4x4 frags 16x16)
// Rows >= split use Bt1 instead of Bt0 (lets one launch do the K and V projections).
template <int OUTF32>
__global__ __launch_bounds__(256, 2) void gemm_bt_kernel(
    const u16* __restrict__ A, const u16* __restrict__ Bt0, const u16* __restrict__ Bt1,
    void* __restrict__ C, int M, int N, int K, int split)
{
  __shared__ u16 As[128 * 64];
  __shared__ u16 Bs[128 * 64];
  const int tid = threadIdx.x;
  const int wave = tid >> 6, lane = tid & 63;
  const int nbx = N >> 7;
  const int bx = blockIdx.x % nbx, by = blockIdx.x / nbx;
  const int row0 = by << 7, col0 = bx << 7;
  const u16* Bt = (row0 >= split) ? Bt1 : Bt0;
  const int wm = wave >> 1, wn = wave & 1;

  f32x4 acc[4][4] = {};

  const int srow = lane >> 3;
  const int sslot = lane & 7;
  const int scol = ((sslot ^ srow) << 3);  // pre-swizzled source col

  for (int k0 = 0; k0 < K; k0 += 64) {
#pragma unroll
    for (int i = 0; i < 4; ++i) {
      int rbase = (wave << 5) + (i << 3);
      const u16* ga = A + (size_t)(row0 + rbase + srow) * K + k0 + scol;
      gload_lds16(ga, &As[rbase << 6]);
      const u16* gb = Bt + (size_t)(col0 + rbase + srow) * K + k0 + scol;
      gload_lds16(gb, &Bs[rbase << 6]);
    }
    __syncthreads();
#pragma unroll
    for (int kk = 0; kk < 2; ++kk) {
      bf16x8 af[4], bfr[4];
      int colb = (kk << 6) + ((lane >> 4) << 4);  // byte col within row
#pragma unroll
      for (int m = 0; m < 4; ++m) {
        int r = (wm << 6) + (m << 4) + (lane & 15);
        af[m] = *(const bf16x8*)((const char*)As + (r << 7) + (colb ^ ((r & 7) << 4)));
      }
#pragma unroll
      for (int n = 0; n < 4; ++n) {
        int r = (wn << 6) + (n << 4) + (lane & 15);
        bfr[n] = *(const bf16x8*)((const char*)Bs + (r << 7) + (colb ^ ((r & 7) << 4)));
      }
#pragma unroll
      for (int m = 0; m < 4; ++m)
#pragma unroll
        for (int n = 0; n < 4; ++n)
          acc[m][n] = __builtin_amdgcn_mfma_f32_16x16x32_bf16(af[m], bfr[n], acc[m][n], 0, 0, 0);
    }
    __syncthreads();
  }

  const int crow = (lane >> 4) << 2;
  const int ccol = lane & 15;
#pragma unroll
  for (int m = 0; m < 4; ++m) {
#pragma unroll
    for (int n = 0; n < 4; ++n) {
      int r = row0 + (wm << 6) + (m << 4) + crow;
      int c = col0 + (wn << 6) + (n << 4) + ccol;
#pragma unroll
      for (int reg = 0; reg < 4; ++reg) {
        if (OUTF32) ((float*)C)[(size_t)(r + reg) * N + c] = acc[m][n][reg];
        else        ((u16*)C)[(size_t)(r + reg) * N + c] = f2b(acc[m][n][reg]);
      }
    }
  }
}

// ---------------- strided-local attention (MFMA) ------------------------------
// Block = (64-query tile jt, head h, batch b). kbase = (j0-124)/4 (exact).
// Query jq attends slab cols [rof, rof+32), rof = jq>>2 in [0,16); valid iff kbase+c >= 0.
// S[64][48] = Q.K^T via mfma; in-register masked softmax; O[64][64] = P[64][64].Vt^T.
#define VTP 56   // Vt pitch (elems): 112B rows, 2-way banks, 16B aligned
#define PLP 72   // Pl pitch (elems): 144B rows, 2-way banks, 16B aligned
__global__ __launch_bounds__(256) void attn_kernel(
    const u16* __restrict__ Qp, const u16* __restrict__ Kp,
    const u16* __restrict__ Vp, u16* __restrict__ Ob)
{
  __shared__ u16 Ql[64 * 64];          // swizzled 128B rows
  __shared__ u16 Kl[48 * 64];          // swizzled 128B rows
  __shared__ u16 Vt[64 * VTP + 64];    // V^T [d][c] + zeroed tail
  __shared__ u16 Pl[64 * PLP];         // P [jq][c], cols 48..63 zeroed

  const int jt = blockIdx.x, h = blockIdx.y, b = blockIdx.z;
  const int j0 = jt << 6;
  const int kbase = (j0 - 124) >> 2;   // exact: j0-124 divisible by 4
  const int tid = threadIdx.x;
  const int wave = tid >> 6, lane = tid & 63;

  // ---- stage Q (64 rows) / K (48 rows) via global_load_lds, XOR-swizzled ----
  const int srow = lane >> 3, sslot = lane & 7;
  const int scol = ((sslot ^ srow) << 3);
  for (int g = wave; g < 8; g += 4) {
    int r = (g << 3) + srow;
    const u16* ga = Qp + (((size_t)(b * 2048 + j0 + r)) << 10) + (h << 6) + scol;
    gload_lds16(ga, &Ql[g << 9]);
  }
  for (int g = wave; g < 6; g += 4) {
    int r = (g << 3) + srow;
    int key = kbase + r;
    key = key < 0 ? 0 : (key > 511 ? 511 : key);
    const u16* gk = Kp + (((size_t)(b * 512 + key)) << 10) + (h << 6) + scol;
    gload_lds16(gk, &Kl[g << 9]);
  }
  // ---- stage V transposed: Vt[d][c] = V[kbase+c][d] ----
  for (int idx = tid; idx < 48 * 8; idx += 256) {
    int row = idx >> 3, seg = idx & 7;
    int key = kbase + row;
    key = key < 0 ? 0 : (key > 511 ? 511 : key);
    uint4 x = *(const uint4*)(Vp + (((size_t)(b * 512 + key)) << 10) + (h << 6) + (seg << 3));
    int d0 = seg << 3;
    Vt[(d0 + 0) * VTP + row] = (u16)(x.x);
    Vt[(d0 + 1) * VTP + row] = (u16)(x.x >> 16);
    Vt[(d0 + 2) * VTP + row] = (u16)(x.y);
    Vt[(d0 + 3) * VTP + row] = (u16)(x.y >> 16);
    Vt[(d0 + 4) * VTP + row] = (u16)(x.z);
    Vt[(d0 + 5) * VTP + row] = (u16)(x.z >> 16);
    Vt[(d0 + 6) * VTP + row] = (u16)(x.w);
    Vt[(d0 + 7) * VTP + row] = (u16)(x.w >> 16);
  }
  // zero Vt cols 48..55 (finite for the PV K=64 over-read) + tail
  if (tid < 64) *(uint4*)&Vt[tid * VTP + 48] = make_uint4(0, 0, 0, 0);
  else if (tid < 72) *(uint4*)&Vt[64 * VTP + ((tid - 64) << 3)] = make_uint4(0, 0, 0, 0);
  __syncthreads();

  // ---- S = Q.K^T : wave m-tile = rows [wave*16, wave*16+16), 3 n-tiles ----
  f32x4 sacc[3] = {};
  const int frow_a = (wave << 4) + (lane & 15);
#pragma unroll
  for (int kk = 0; kk < 2; ++kk) {
    int colb = (kk << 6) + ((lane >> 4) << 4);
    bf16x8 aq = *(const bf16x8*)((const char*)Ql + (frow_a << 7) + (colb ^ ((frow_a & 7) << 4)));
#pragma unroll
    for (int nt = 0; nt < 3; ++nt) {
      int rk = (nt << 4) + (lane & 15);
      bf16x8 bk = *(const bf16x8*)((const char*)Kl + (rk << 7) + (colb ^ ((rk & 7) << 4)));
      sacc[nt] = __builtin_amdgcn_mfma_f32_16x16x32_bf16(aq, bk, sacc[nt], 0, 0, 0);
    }
  }

  // ---- masked softmax, fully in-register (rof uniform per lane) ----
  const int rof = (wave << 2) + (lane >> 4);
  const int cb0 = lane & 15;
  bool vld[3]; float sc[3][4];
#pragma unroll
  for (int nt = 0; nt < 3; ++nt) {
    int c = cb0 + (nt << 4);
    vld[nt] = ((unsigned)(c - rof) < 32u) && (kbase + c >= 0);
#pragma unroll
    for (int r = 0; r < 4; ++r) sc[nt][r] = sacc[nt][r] * 0.125f;
  }
  float mx[4], rs[4];
#pragma unroll
  for (int r = 0; r < 4; ++r) {
    float m = -3.0e38f;
#pragma unroll
    for (int nt = 0; nt < 3; ++nt) m = vld[nt] ? fmaxf(m, sc[nt][r]) : m;
    m = fmaxf(m, __shfl_xor(m, 1));
    m = fmaxf(m, __shfl_xor(m, 2));
    m = fmaxf(m, __shfl_xor(m, 4));
    m = fmaxf(m, __shfl_xor(m, 8));
    mx[r] = m;
  }
#pragma unroll
  for (int r = 0; r < 4; ++r) {
    float s = 0.f;
#pragma unroll
    for (int nt = 0; nt < 3; ++nt) {
      float e = vld[nt] ? __expf(sc[nt][r] - mx[r]) : 0.f;
      sc[nt][r] = e;
      s += e;
    }
    s += __shfl_xor(s, 1);
    s += __shfl_xor(s, 2);
    s += __shfl_xor(s, 4);
    s += __shfl_xor(s, 8);
    rs[r] = 1.f / s;
  }
  // write P bf16 rows (cols 0..47 real, 48..63 zero)
#pragma unroll
  for (int r = 0; r < 4; ++r) {
    int jq = (wave << 4) + ((lane >> 4) << 2) + r;
#pragma unroll
    for (int nt = 0; nt < 3; ++nt)
      Pl[jq * PLP + cb0 + (nt << 4)] = f2b(sc[nt][r] * rs[r]);
    Pl[jq * PLP + 48 + cb0] = 0;
  }
  __syncthreads();

  // ---- O = P.V : A-frags from Pl, B-frags from Vt, K=64, 4 n-tiles ----
  f32x4 oacc[4] = {};
#pragma unroll
  for (int kk = 0; kk < 2; ++kk) {
    int koff = (kk << 5) + ((lane >> 4) << 3);
    bf16x8 ap = *(const bf16x8*)&Pl[frow_a * PLP + koff];
#pragma unroll
    for (int nt = 0; nt < 4; ++nt) {
      int dr = (nt << 4) + (lane & 15);
      bf16x8 bv = *(const bf16x8*)&Vt[dr * VTP + koff];
      oacc[nt] = __builtin_amdgcn_mfma_f32_16x16x32_bf16(ap, bv, oacc[nt], 0, 0, 0);
    }
  }

  // ---- write O ----
#pragma unroll
  for (int nt = 0; nt < 4; ++nt) {
    int d = (nt << 4) + (lane & 15);
#pragma unroll
    for (int r = 0; r < 4; ++r) {
      int jq = (wave << 4) + ((lane >> 4) << 2) + r;
      Ob[(((size_t)(b * 2048 + j0 + jq)) << 10) + (h << 6) + d] = f2b(oacc[nt][r]);
    }
  }
}

extern "C" void kernel_launch(void* const* d_in, const int* in_sizes, int n_in,
                              void* d_out, int out_size, void* d_ws, size_t ws_size,
                              hipStream_t stream) {
  const float* q  = (const float*)d_in[0];
  const float* k  = (const float*)d_in[1];
  const float* v  = (const float*)d_in[2];
  const float* Wq = (const float*)d_in[3];
  const float* Wk = (const float*)d_in[4];
  const float* Wv = (const float*)d_in[5];
  const float* Wo = (const float*)d_in[6];

  char* ws = (char*)d_ws;
  const size_t MB = 1u << 20;
  u16* qb  = (u16*)(ws + 0 * MB);    // 8 MB
  u16* kb  = (u16*)(ws + 8 * MB);    // 2 MB  (kb||vb contiguous)
  u16* vb  = (u16*)(ws + 10 * MB);   // 2 MB
  u16* Wqt = (u16*)(ws + 12 * MB);   // 2 MB
  u16* Wkt = (u16*)(ws + 14 * MB);
  u16* Wvt = (u16*)(ws + 16 * MB);
  u16* Wot = (u16*)(ws + 18 * MB);
  u16* Qp  = (u16*)(ws + 20 * MB);   // 8 MB
  u16* Kp  = (u16*)(ws + 28 * MB);   // 2 MB  (Kp||Vp contiguous)
  u16* Vp  = (u16*)(ws + 30 * MB);   // 2 MB
  u16* Ob  = (u16*)(ws + 32 * MB);   // 8 MB  (total 40 MB)

  const int HUGE_SPLIT = 1 << 30;

  // 1) convert inputs to bf16
  cvt3_kernel<<<6144, 256, 0, stream>>>(q, k, v, qb, kb, vb);
  // 2) transpose+convert all 4 weight matrices
  transpose_cvt_kernel<<<dim3(32, 32, 4), 256, 0, stream>>>(Wq, Wk, Wv, Wo, Wqt, Wkt, Wvt, Wot);
  // 3) projections: Q alone; K and V merged into one M=2048 launch (B switches at row 1024)
  gemm_bt_kernel<0><<<256, 256, 0, stream>>>(qb, Wqt, Wqt, Qp, 4096, 1024, 1024, HUGE_SPLIT);
  gemm_bt_kernel<0><<<128, 256, 0, stream>>>(kb, Wkt, Wvt, Kp, 2048, 1024, 1024, 1024);
  // 4) attention (MFMA)
  attn_kernel<<<dim3(32, 16, 2), 256, 0, stream>>>(Qp, Kp, Vp, Ob);
  // 5) output projection (f32 out)
  gemm_bt_kernel<1><<<256, 256, 0, stream>>>(Ob, Wot, Wot, d_out, 4096, 1024, 1024, HUGE_SPLIT);
}

// Round 3
// 60.785 us; speedup vs baseline: 2.5498x; 1.4303x over previous
//
#include <hip/hip_runtime.h>
#include <hip/hip_bf16.h>

typedef __bf16 bf16x8 __attribute__((ext_vector_type(8)));
typedef float  f32x4  __attribute__((ext_vector_type(4)));
typedef unsigned short u16;
typedef unsigned int   u32;

__device__ __forceinline__ u16 f2b(float x) {
  __bf16 b = (__bf16)x;
  return __builtin_bit_cast(u16, b);
}

__device__ __forceinline__ void gload_lds16(const u16* g, u16* l) {
  __builtin_amdgcn_global_load_lds(
      (const __attribute__((address_space(1))) void*)g,
      (__attribute__((address_space(3))) void*)l, 16, 0, 0);
}

// ---------------- prep: cvt q/k/v f32->bf16  +  transpose+cvt 4 weights ------
#define Q4 1048576   // 2*2048*1024/4
#define K4 262144    // 2*512*1024/4
#define CVT_BLOCKS 6144
__global__ __launch_bounds__(256) void prep_kernel(
    const float* __restrict__ q, const float* __restrict__ k, const float* __restrict__ v,
    u16* __restrict__ qb, u16* __restrict__ kb, u16* __restrict__ vb,
    const float* __restrict__ W0, const float* __restrict__ W1,
    const float* __restrict__ W2, const float* __restrict__ W3,
    u16* __restrict__ T0, u16* __restrict__ T1, u16* __restrict__ T2, u16* __restrict__ T3)
{
  __shared__ float tile[32][33];
  int bid = blockIdx.x;
  if (bid < CVT_BLOCKS) {
    int i = bid * 256 + threadIdx.x;
    const float* src; u16* dst; int off;
    if (i < Q4)            { src = q; dst = qb; off = i; }
    else if (i < Q4 + K4)  { src = k; dst = kb; off = i - Q4; }
    else                   { src = v; dst = vb; off = i - Q4 - K4; }
    float4 x = ((const float4*)src)[off];
    ushort4 r;
    r.x = f2b(x.x); r.y = f2b(x.y); r.z = f2b(x.z); r.w = f2b(x.w);
    ((ushort4*)dst)[off] = r;
  } else {
    int t = bid - CVT_BLOCKS;
    int z = t >> 10, rem = t & 1023;
    const float* W = (z == 0) ? W0 : (z == 1) ? W1 : (z == 2) ? W2 : W3;
    u16* T = (z == 0) ? T0 : (z == 1) ? T1 : (z == 2) ? T2 : T3;
    int tx = threadIdx.x & 31, ty = threadIdx.x >> 5;
    int c0 = (rem & 31) << 5, r0 = (rem >> 5) << 5;
#pragma unroll
    for (int i = 0; i < 4; ++i)
      tile[ty + i * 8][tx] = W[(size_t)(r0 + ty + i * 8) * 1024 + c0 + tx];
    __syncthreads();
#pragma unroll
    for (int i = 0; i < 4; ++i)
      T[(size_t)(c0 + ty + i * 8) * 1024 + r0 + tx] = f2b(tile[tx][ty + i * 8]);
  }
}

// ---------------- bf16 MFMA GEMM core: C[.,N] tile = A[M,K] * Bt[N,K]^T ------
// BM=BN=128, BK=64, 256 threads (4 waves, 2x2), double-buffered LDS,
// next-tile global_load_lds issued BEFORE current-tile compute (T3 2-phase).
template <int OUTF32>
__device__ __forceinline__ void gemm_core(
    const u16* __restrict__ A, const u16* __restrict__ Bt, void* __restrict__ C,
    int N, int K, int row0, int col0,
    u16* As0, u16* As1, u16* Bs0, u16* Bs1)
{
  const int tid = threadIdx.x;
  const int wave = tid >> 6, lane = tid & 63;
  const int wm = wave >> 1, wn = wave & 1;

  f32x4 acc[4][4] = {};

  const int srow = lane >> 3, sslot = lane & 7;
  const int scol = ((sslot ^ srow) << 3);  // pre-swizzled source col

  const u16* gA = A + (size_t)(row0 + (wave << 5) + srow) * K + scol;
  const u16* gB = Bt + (size_t)(col0 + (wave << 5) + srow) * K + scol;

#define STAGE(as, bs, k0) do {                                           \
    _Pragma("unroll")                                                    \
    for (int i_ = 0; i_ < 4; ++i_) {                                     \
      int rb_ = (wave << 5) + (i_ << 3);                                 \
      gload_lds16(gA + (size_t)(i_ << 3) * K + (k0), (as) + (rb_ << 6)); \
      gload_lds16(gB + (size_t)(i_ << 3) * K + (k0), (bs) + (rb_ << 6)); \
    } } while (0)

  STAGE(As0, Bs0, 0);
  __syncthreads();

  u16 *asc = As0, *bsc = Bs0, *asn = As1, *bsn = Bs1;
  for (int k0 = 0; k0 < K; k0 += 64) {
    if (k0 + 64 < K) STAGE(asn, bsn, k0 + 64);   // prefetch flies under MFMA
#pragma unroll
    for (int kk = 0; kk < 2; ++kk) {
      bf16x8 af[4], bfr[4];
      int colb = (kk << 6) + ((lane >> 4) << 4);  // byte col within 128B row
#pragma unroll
      for (int m = 0; m < 4; ++m) {
        int r = (wm << 6) + (m << 4) + (lane & 15);
        af[m] = *(const bf16x8*)((const char*)asc + (r << 7) + (colb ^ ((r & 7) << 4)));
      }
#pragma unroll
      for (int n = 0; n < 4; ++n) {
        int r = (wn << 6) + (n << 4) + (lane & 15);
        bfr[n] = *(const bf16x8*)((const char*)bsc + (r << 7) + (colb ^ ((r & 7) << 4)));
      }
#pragma unroll
      for (int m = 0; m < 4; ++m)
#pragma unroll
        for (int n = 0; n < 4; ++n)
          acc[m][n] = __builtin_amdgcn_mfma_f32_16x16x32_bf16(af[m], bfr[n], acc[m][n], 0, 0, 0);
    }
    __syncthreads();  // drains vmcnt(0): prefetch landed, all waves done with asc/bsc
    u16* t_;
    t_ = asc; asc = asn; asn = t_;
    t_ = bsc; bsc = bsn; bsn = t_;
  }
#undef STAGE

  const int crow = (lane >> 4) << 2;
  const int ccol = lane & 15;
#pragma unroll
  for (int m = 0; m < 4; ++m) {
#pragma unroll
    for (int n = 0; n < 4; ++n) {
      int r = row0 + (wm << 6) + (m << 4) + crow;
      int c = col0 + (wn << 6) + (n << 4) + ccol;
#pragma unroll
      for (int reg = 0; reg < 4; ++reg) {
        if (OUTF32) ((float*)C)[(size_t)(r + reg) * N + c] = acc[m][n][reg];
        else        ((u16*)C)[(size_t)(r + reg) * N + c] = f2b(acc[m][n][reg]);
      }
    }
  }
}

// out projection (f32 out)
template <int OUTF32>
__global__ __launch_bounds__(256, 2) void gemm_bt_kernel(
    const u16* __restrict__ A, const u16* __restrict__ Bt, void* __restrict__ C,
    int M, int N, int K)
{
  __shared__ u16 As[2][8192];
  __shared__ u16 Bs[2][8192];
  const int nbx = N >> 7;
  const int bx = blockIdx.x % nbx, by = blockIdx.x / nbx;
  gemm_core<OUTF32>(A, Bt, C, N, K, by << 7, bx << 7, As[0], As[1], Bs[0], Bs[1]);
}

// fused Q + K + V projections in one launch (384 blocks)
__global__ __launch_bounds__(256, 2) void proj_kernel(
    const u16* __restrict__ qb, const u16* __restrict__ kvb,
    const u16* __restrict__ Wqt, const u16* __restrict__ Wkt, const u16* __restrict__ Wvt,
    u16* __restrict__ Qp, u16* __restrict__ KVp)
{
  __shared__ u16 As[2][8192];
  __shared__ u16 Bs[2][8192];
  int bid = blockIdx.x;
  const u16 *A, *Bt; u16* C; int row0, col0;
  if (bid < 256) {                       // Q projection: M=4096
    A = qb; Bt = Wqt; C = Qp;
    row0 = (bid >> 3) << 7; col0 = (bid & 7) << 7;
  } else {                               // K/V projections: M=2048 (B switches at row 1024)
    int t = bid - 256;
    row0 = (t >> 3) << 7; col0 = (t & 7) << 7;
    A = kvb; C = KVp;
    Bt = (row0 >= 1024) ? Wvt : Wkt;
  }
  gemm_core<0>(A, Bt, C, 1024, 1024, row0, col0, As[0], As[1], Bs[0], Bs[1]);
}

// ---------------- strided-local attention (MFMA) ------------------------------
// Block = (64-query tile jt, head h, batch b). kbase = (j0-124)/4 (exact).
// Query jq attends slab cols [rof, rof+32), rof = jq>>2 in [0,16); valid iff kbase+c >= 0.
#define VTP 56   // Vt pitch (elems)
#define PLP 72   // Pl pitch (elems)
__global__ __launch_bounds__(256) void attn_kernel(
    const u16* __restrict__ Qp, const u16* __restrict__ Kp,
    const u16* __restrict__ Vp, u16* __restrict__ Ob)
{
  __shared__ u16 Ql[64 * 64];          // swizzled 128B rows
  __shared__ u16 Kl[48 * 64];          // swizzled 128B rows
  __shared__ u16 Vt[64 * VTP + 64];    // V^T [d][c] + zeroed tail
  __shared__ u16 Pl[64 * PLP];         // P [jq][c], cols 48..63 zeroed

  const int jt = blockIdx.x, h = blockIdx.y, b = blockIdx.z;
  const int j0 = jt << 6;
  const int kbase = (j0 - 124) >> 2;
  const int tid = threadIdx.x;
  const int wave = tid >> 6, lane = tid & 63;

  const int srow = lane >> 3, sslot = lane & 7;
  const int scol = ((sslot ^ srow) << 3);
  for (int g = wave; g < 8; g += 4) {
    int r = (g << 3) + srow;
    const u16* ga = Qp + (((size_t)(b * 2048 + j0 + r)) << 10) + (h << 6) + scol;
    gload_lds16(ga, &Ql[g << 9]);
  }
  for (int g = wave; g < 6; g += 4) {
    int r = (g << 3) + srow;
    int key = kbase + r;
    key = key < 0 ? 0 : (key > 511 ? 511 : key);
    const u16* gk = Kp + (((size_t)(b * 512 + key)) << 10) + (h << 6) + scol;
    gload_lds16(gk, &Kl[g << 9]);
  }
  for (int idx = tid; idx < 48 * 8; idx += 256) {
    int row = idx >> 3, seg = idx & 7;
    int key = kbase + row;
    key = key < 0 ? 0 : (key > 511 ? 511 : key);
    uint4 x = *(const uint4*)(Vp + (((size_t)(b * 512 + key)) << 10) + (h << 6) + (seg << 3));
    int d0 = seg << 3;
    Vt[(d0 + 0) * VTP + row] = (u16)(x.x);
    Vt[(d0 + 1) * VTP + row] = (u16)(x.x >> 16);
    Vt[(d0 + 2) * VTP + row] = (u16)(x.y);
    Vt[(d0 + 3) * VTP + row] = (u16)(x.y >> 16);
    Vt[(d0 + 4) * VTP + row] = (u16)(x.z);
    Vt[(d0 + 5) * VTP + row] = (u16)(x.z >> 16);
    Vt[(d0 + 6) * VTP + row] = (u16)(x.w);
    Vt[(d0 + 7) * VTP + row] = (u16)(x.w >> 16);
  }
  if (tid < 64) *(uint4*)&Vt[tid * VTP + 48] = make_uint4(0, 0, 0, 0);
  else if (tid < 72) *(uint4*)&Vt[64 * VTP + ((tid - 64) << 3)] = make_uint4(0, 0, 0, 0);
  __syncthreads();

  f32x4 sacc[3] = {};
  const int frow_a = (wave << 4) + (lane & 15);
#pragma unroll
  for (int kk = 0; kk < 2; ++kk) {
    int colb = (kk << 6) + ((lane >> 4) << 4);
    bf16x8 aq = *(const bf16x8*)((const char*)Ql + (frow_a << 7) + (colb ^ ((frow_a & 7) << 4)));
#pragma unroll
    for (int nt = 0; nt < 3; ++nt) {
      int rk = (nt << 4) + (lane & 15);
      bf16x8 bk = *(const bf16x8*)((const char*)Kl + (rk << 7) + (colb ^ ((rk & 7) << 4)));
      sacc[nt] = __builtin_amdgcn_mfma_f32_16x16x32_bf16(aq, bk, sacc[nt], 0, 0, 0);
    }
  }

  const int rof = (wave << 2) + (lane >> 4);
  const int cb0 = lane & 15;
  bool vld[3]; float sc[3][4];
#pragma unroll
  for (int nt = 0; nt < 3; ++nt) {
    int c = cb0 + (nt << 4);
    vld[nt] = ((unsigned)(c - rof) < 32u) && (kbase + c >= 0);
#pragma unroll
    for (int r = 0; r < 4; ++r) sc[nt][r] = sacc[nt][r] * 0.125f;
  }
  float mx[4], rs[4];
#pragma unroll
  for (int r = 0; r < 4; ++r) {
    float m = -3.0e38f;
#pragma unroll
    for (int nt = 0; nt < 3; ++nt) m = vld[nt] ? fmaxf(m, sc[nt][r]) : m;
    m = fmaxf(m, __shfl_xor(m, 1));
    m = fmaxf(m, __shfl_xor(m, 2));
    m = fmaxf(m, __shfl_xor(m, 4));
    m = fmaxf(m, __shfl_xor(m, 8));
    mx[r] = m;
  }
#pragma unroll
  for (int r = 0; r < 4; ++r) {
    float s = 0.f;
#pragma unroll
    for (int nt = 0; nt < 3; ++nt) {
      float e = vld[nt] ? __expf(sc[nt][r] - mx[r]) : 0.f;
      sc[nt][r] = e;
      s += e;
    }
    s += __shfl_xor(s, 1);
    s += __shfl_xor(s, 2);
    s += __shfl_xor(s, 4);
    s += __shfl_xor(s, 8);
    rs[r] = 1.f / s;
  }
#pragma unroll
  for (int r = 0; r < 4; ++r) {
    int jq = (wave << 4) + ((lane >> 4) << 2) + r;
#pragma unroll
    for (int nt = 0; nt < 3; ++nt)
      Pl[jq * PLP + cb0 + (nt << 4)] = f2b(sc[nt][r] * rs[r]);
    Pl[jq * PLP + 48 + cb0] = 0;
  }
  __syncthreads();

  f32x4 oacc[4] = {};
#pragma unroll
  for (int kk = 0; kk < 2; ++kk) {
    int koff = (kk << 5) + ((lane >> 4) << 3);
    bf16x8 ap = *(const bf16x8*)&Pl[frow_a * PLP + koff];
#pragma unroll
    for (int nt = 0; nt < 4; ++nt) {
      int dr = (nt << 4) + (lane & 15);
      bf16x8 bv = *(const bf16x8*)&Vt[dr * VTP + koff];
      oacc[nt] = __builtin_amdgcn_mfma_f32_16x16x32_bf16(ap, bv, oacc[nt], 0, 0, 0);
    }
  }

#pragma unroll
  for (int nt = 0; nt < 4; ++nt) {
    int d = (nt << 4) + (lane & 15);
#pragma unroll
    for (int r = 0; r < 4; ++r) {
      int jq = (wave << 4) + ((lane >> 4) << 2) + r;
      Ob[(((size_t)(b * 2048 + j0 + jq)) << 10) + (h << 6) + d] = f2b(oacc[nt][r]);
    }
  }
}

extern "C" void kernel_launch(void* const* d_in, const int* in_sizes, int n_in,
                              void* d_out, int out_size, void* d_ws, size_t ws_size,
                              hipStream_t stream) {
  const float* q  = (const float*)d_in[0];
  const float* k  = (const float*)d_in[1];
  const float* v  = (const float*)d_in[2];
  const float* Wq = (const float*)d_in[3];
  const float* Wk = (const float*)d_in[4];
  const float* Wv = (const float*)d_in[5];
  const float* Wo = (const float*)d_in[6];

  char* ws = (char*)d_ws;
  const size_t MB = 1u << 20;
  u16* qb  = (u16*)(ws + 0 * MB);    // 8 MB
  u16* kb  = (u16*)(ws + 8 * MB);    // 2 MB  (kb||vb contiguous)
  u16* vb  = (u16*)(ws + 10 * MB);   // 2 MB
  u16* Wqt = (u16*)(ws + 12 * MB);   // 2 MB
  u16* Wkt = (u16*)(ws + 14 * MB);
  u16* Wvt = (u16*)(ws + 16 * MB);
  u16* Wot = (u16*)(ws + 18 * MB);
  u16* Qp  = (u16*)(ws + 20 * MB);   // 8 MB
  u16* Kp  = (u16*)(ws + 28 * MB);   // 2 MB  (Kp||Vp contiguous)
  u16* Vp  = (u16*)(ws + 30 * MB);   // 2 MB
  u16* Ob  = (u16*)(ws + 32 * MB);   // 8 MB  (total 40 MB)

  // 1) prep: convert q/k/v to bf16 + transpose/convert the 4 weight matrices
  prep_kernel<<<CVT_BLOCKS + 4096, 256, 0, stream>>>(
      q, k, v, qb, kb, vb, Wq, Wk, Wv, Wo, Wqt, Wkt, Wvt, Wot);
  // 2) all three projections in one launch
  proj_kernel<<<384, 256, 0, stream>>>(qb, kb, Wqt, Wkt, Wvt, Qp, Kp);
  // 3) attention (MFMA)
  attn_kernel<<<dim3(32, 16, 2), 256, 0, stream>>>(Qp, Kp, Vp, Ob);
  // 4) output projection (f32 out)
  gemm_bt_kernel<1><<<256, 256, 0, stream>>>(Ob, Wot, d_out, 4096, 1024, 1024);
}